// Round 12
// baseline (119.822 us; speedup 1.0000x reference)
//
#include <hip/hip_runtime.h>
#include <hip/hip_bf16.h>

#define N_NODES 40000
#define N_EDGES 640000
#define N_GRAPH 64
#define C_IN 64
#define HID 128
#define OUT 128
#define ZDIM 192   // HID + C_IN
#define CAP 64     // fixed bucket stride; P(in-degree > 64) ~ 1e-17, guarded anyway

typedef __bf16 bf16x8 __attribute__((ext_vector_type(8)));
typedef float  f32x4  __attribute__((ext_vector_type(4)));

__device__ __forceinline__ unsigned short f2bf(float f) {
  unsigned u = __float_as_uint(f);
  unsigned r = (u + 0x7FFFu + ((u >> 16) & 1u)) >> 16;
  return (unsigned short)r;
}

__device__ __forceinline__ void bf8_add(float* acc, uint4 r) {
  acc[0] += __uint_as_float(r.x << 16);
  acc[1] += __uint_as_float(r.x & 0xFFFF0000u);
  acc[2] += __uint_as_float(r.y << 16);
  acc[3] += __uint_as_float(r.y & 0xFFFF0000u);
  acc[4] += __uint_as_float(r.z << 16);
  acc[5] += __uint_as_float(r.z & 0xFFFF0000u);
  acc[6] += __uint_as_float(r.w << 16);
  acc[7] += __uint_as_float(r.w & 0xFFFF0000u);
}

__device__ __forceinline__ void bf8_set(float* acc, uint4 r) {
  acc[0] = __uint_as_float(r.x << 16);
  acc[1] = __uint_as_float(r.x & 0xFFFF0000u);
  acc[2] = __uint_as_float(r.y << 16);
  acc[3] = __uint_as_float(r.y & 0xFFFF0000u);
  acc[4] = __uint_as_float(r.z << 16);
  acc[5] = __uint_as_float(r.z & 0xFFFF0000u);
  acc[6] = __uint_as_float(r.w << 16);
  acc[7] = __uint_as_float(r.w & 0xFFFF0000u);
}

// ---------------------------------------------------------------------------
// K1: bucketed CSR build + wc2t transform; LAST block does weight-prep
// concurrently (hides its ~6us under the 20us edge scatter).
// Weight-prep stages 16KB LDS chunks so k_build keeps >=8 blocks/CU.
__global__ __launch_bounds__(256) void k_build(
    const int* __restrict__ src, const int* __restrict__ dst,
    int* __restrict__ cursor, int* __restrict__ csrf,
    const float* __restrict__ Wc2, __bf16* __restrict__ wc2t,
    const float* __restrict__ W1, const float* __restrict__ b1,
    const float* __restrict__ W2, const float* __restrict__ b2,
    const float* __restrict__ W3, const float* __restrict__ b3,
    const float* __restrict__ Wc1,
    float* __restrict__ wv, float* __restrict__ bv,
    float* __restrict__ wc, float* __restrict__ bcv) {
  __shared__ __align__(16) float stage[4096];   // 16 KB
  __shared__ float t1[256], u1[256], wv_s[64], bv_s[64], w1s[64], b1s[64];
  int t = threadIdx.x;

  if (blockIdx.x == gridDim.x - 1) {
    // ---------------- weight-prep path (one block) ----------------
    float4* sv = (float4*)stage;
    float s1 = 0.f, s2 = 0.f;
    if (t < 64) { w1s[t] = W1[t]; b1s[t] = b1[t]; }
    // phase A: t1/u1 = (W1|b1) @ W2 ; W2 = 64x256, 4 chunks of 16 rows
    for (int ch = 0; ch < 4; ++ch) {
      const float4* W2v = (const float4*)(W2 + ch * 16 * 256);
      __syncthreads();
      for (int i = t; i < 1024; i += 256) sv[i] = W2v[i];
      __syncthreads();
      for (int j = 0; j < 16; ++j) {
        float w = stage[j * 256 + t];
        s1 += w1s[ch * 16 + j] * w;
        s2 += b1s[ch * 16 + j] * w;
      }
    }
    t1[t] = s1;
    u1[t] = s2 + b2[t];
    // phase B: wv/bv = (t1|u1) @ W3 + b3 ; W3 = 256x64, 4 chunks of 64 rows
    float a = 0.f, bb = 0.f;
    for (int ch = 0; ch < 4; ++ch) {
      const float4* W3v = (const float4*)(W3 + ch * 64 * 64);
      __syncthreads();
      for (int i = t; i < 1024; i += 256) sv[i] = W3v[i];
      __syncthreads();
      if (t < 64) {
        for (int k = 0; k < 64; ++k) {
          float w = stage[k * 64 + t];
          a += t1[ch * 64 + k] * w;
          bb += u1[ch * 64 + k] * w;
        }
      }
    }
    if (t < 64) {
      bb += b3[t];
      wv_s[t] = a; bv_s[t] = bb;
      wv[t] = a;  bv[t] = bb;
    }
    // phase C: wc/bcv = (wv|bv) @ Wc1 ; Wc1 = 64x128, 2 chunks of 32 rows
    float aa = 0.f, bb2 = 0.f;
    for (int ch = 0; ch < 2; ++ch) {
      const float4* Wc1v = (const float4*)(Wc1 + ch * 32 * 128);
      __syncthreads();
      for (int i = t; i < 1024; i += 256) sv[i] = Wc1v[i];
      __syncthreads();
      if (t < 128) {
        for (int c = 0; c < 32; ++c) {
          float w = stage[c * 128 + t];
          aa += wv_s[ch * 32 + c] * w;
          bb2 += bv_s[ch * 32 + c] * w;
        }
      }
    }
    if (t < 128) { wc[t] = aa; bcv[t] = bb2; }
    return;
  }

  // ---------------- edge path ----------------
  int e = blockIdx.x * blockDim.x + t;
  if (e < 128 * ZDIM) {
    int col = e & 127, k = e >> 7;        // coalesced read of Wc2[k*128+col]
    int ct = col >> 4, lr = col & 15;
    int kk = k >> 5, lg = (k >> 3) & 3, jj = k & 7;
    wc2t[((ct * 6 + kk) * 64 + lg * 16 + lr) * 8 + jj] = (__bf16)Wc2[e];
  }
  if (e < N_EDGES) {
    int d = dst[e];
    int p = atomicAdd(&cursor[d], 1);
    if (p < CAP) csrf[d * CAP + p] = src[e];
  }
}

// ---------------------------------------------------------------------------
// K2: dinv[v] = rsqrt(deg+1) + per-graph segment bounds (40 blocks, ~2us)
__global__ __launch_bounds__(256) void k_prep2(
    const int* __restrict__ cursor, float* __restrict__ dinv,
    const int* __restrict__ batch, int* __restrict__ start) {
  int t = threadIdx.x;
  int base = blockIdx.x * 1024;
  for (int i = 0; i < 4; ++i) {
    int v = base + t * 4 + i;
    if (v < N_NODES) {
      dinv[v] = 1.0f / sqrtf((float)(cursor[v] + 1));
      int bv2 = batch[v];
      if (v == 0) {
        for (int b = 0; b <= bv2; ++b) start[b] = 0;
      } else {
        int bp = batch[v - 1];
        for (int b = bp + 1; b <= bv2; ++b) start[b] = v;
      }
      if (v == N_NODES - 1) {
        for (int b = bv2 + 1; b <= N_GRAPH; ++b) start[b] = N_NODES;
      }
    }
  }
}

// K3 (MFMA, no big LDS): per block = 64 nodes, 256 thr = 4 waves.
__global__ __launch_bounds__(256) void k_mlp2(
    const float* __restrict__ x, const int* __restrict__ batch,
    const int* __restrict__ root, const float* __restrict__ dinv,
    const int* __restrict__ cursor, const int* __restrict__ csrf,
    const float* __restrict__ wc, const float* __restrict__ bcv,
    const float* __restrict__ bc1, const float* __restrict__ wv,
    const float* __restrict__ bv, const __bf16* __restrict__ wc2t,
    float* __restrict__ sx, float* __restrict__ sd,
    unsigned short* __restrict__ hW2g) {
  __shared__ float s_dv[64], s_a[64], s_c[64], s_xr[64];
  int t = threadIdx.x;
  int v0 = blockIdx.x * 64;

  // fused sxsd gather: 4 lanes per node, bucket layout
  {
    int g4 = t >> 2, l4 = t & 3;
    int v = v0 + g4;
    int dg = cursor[v]; if (dg > CAP) dg = CAP;
    int o0 = v * CAP;
    float ax = 0.f, ad = 0.f;
    for (int i = l4; i < dg; i += 4) {
      int s = csrf[o0 + i];
      float ds = dinv[s];
      ax += ds * x[s];
      ad += ds;
    }
    ax += __shfl_xor(ax, 1, 4); ad += __shfl_xor(ad, 1, 4);
    ax += __shfl_xor(ax, 2, 4); ad += __shfl_xor(ad, 2, 4);
    if (l4 == 0) {
      float dv = dinv[v];
      float sxv = ax + dv * x[v];
      float sdv = ad + dv;
      sx[v] = sxv; sd[v] = sdv;
      s_dv[g4] = dv;
      s_a[g4] = dv * sxv;
      s_c[g4] = dv * sdv;
      s_xr[g4] = x[root[batch[v]]];
    }
  }
  __syncthreads();

  int w = t >> 6, l = t & 63;
  int rb = w * 16;
  int lr = l & 15, lg = l >> 4;
  int row = rb + lr;

  // A-fragments in registers: af[kk][j] = relu(z[row][kk*32+lg*8+j]) as bf16.
  float a = s_a[row], c = s_c[row], xr = s_xr[row];
  bf16x8 af[6];
#pragma unroll
  for (int kk = 0; kk < 4; ++kk) {
    int k0 = kk * 32 + lg * 8;
#pragma unroll
    for (int j = 0; j < 8; ++j) {
      float val = a * wc[k0 + j] + c * bcv[k0 + j] + bc1[k0 + j];
      af[kk][j] = (__bf16)(val > 0.f ? val : 0.f);
    }
  }
#pragma unroll
  for (int kk = 4; kk < 6; ++kk) {
    int k0 = (kk - 4) * 32 + lg * 8;
#pragma unroll
    for (int j = 0; j < 8; ++j) {
      float val = xr * wv[k0 + j] + bv[k0 + j];
      af[kk][j] = (__bf16)(val > 0.f ? val : 0.f);
    }
  }

  float dvr[4];
#pragma unroll
  for (int reg = 0; reg < 4; ++reg) dvr[reg] = s_dv[rb + lg * 4 + reg];

  const bf16x8* wt = (const bf16x8*)wc2t;
#pragma unroll
  for (int ct = 0; ct < 8; ++ct) {
    f32x4 acc = {0.f, 0.f, 0.f, 0.f};
#pragma unroll
    for (int kk = 0; kk < 6; ++kk) {
      bf16x8 bf = wt[(ct * 6 + kk) * 64 + l];  // coalesced 16B/lane, L2-hot
      acc = __builtin_amdgcn_mfma_f32_16x16x32_bf16(af[kk], bf, acc, 0, 0, 0);
    }
#pragma unroll
    for (int reg = 0; reg < 4; ++reg) {
      int v = v0 + rb + lg * 4 + reg;
      hW2g[(size_t)v * 128 + ct * 16 + lr] = f2bf(dvr[reg] * acc[reg]);
    }
  }
}

// K4: conv2 gather (bucket CSR, bf16 rows, 16 lanes/row) + relu + per-graph
// partial flush. Latency-bound -> 16-row batched round first (16 independent
// loads in flight; covers whole list for ~54% of Poisson-16 nodes), then 8/4/1.
#define GNPB 16
__global__ __launch_bounds__(256) void k_conv2(
    const int* __restrict__ cursor, const int* __restrict__ csrf,
    const uint4* __restrict__ hW2g,  // [N][16] uint4 = 128 bf16/row
    const float* __restrict__ dinv, const float* __restrict__ bc2,
    const int* __restrict__ batch, float* __restrict__ gsum) {
  __shared__ float s_out[GNPB][128];
  __shared__ int s_b[GNPB];
  int t = threadIdx.x;
  int g = t >> 4, l = t & 15;
  int v0 = blockIdx.x * GNPB;
  int v = v0 + g;
  if (t < GNPB) s_b[t] = batch[v0 + t];

  {
    const uint4* bp = hW2g + l;
    float acc[8];
    bf8_set(acc, bp[(size_t)v * 16]);    // self-loop row
    int dg = cursor[v]; if (dg > CAP) dg = CAP;
    int i = v * CAP;
    int e = i + dg;
    for (; i + 16 <= e; i += 16) {
      int s[16];
#pragma unroll
      for (int q = 0; q < 16; ++q) s[q] = csrf[i + q];
      uint4 r[16];
#pragma unroll
      for (int q = 0; q < 16; ++q) r[q] = bp[(size_t)s[q] * 16];
#pragma unroll
      for (int q = 0; q < 16; ++q) bf8_add(acc, r[q]);
    }
    for (; i + 8 <= e; i += 8) {
      int s0 = csrf[i],     s1 = csrf[i + 1], s2 = csrf[i + 2], s3 = csrf[i + 3];
      int s4 = csrf[i + 4], s5 = csrf[i + 5], s6 = csrf[i + 6], s7 = csrf[i + 7];
      uint4 r0 = bp[(size_t)s0 * 16];
      uint4 r1 = bp[(size_t)s1 * 16];
      uint4 r2 = bp[(size_t)s2 * 16];
      uint4 r3 = bp[(size_t)s3 * 16];
      uint4 r4 = bp[(size_t)s4 * 16];
      uint4 r5 = bp[(size_t)s5 * 16];
      uint4 r6 = bp[(size_t)s6 * 16];
      uint4 r7 = bp[(size_t)s7 * 16];
      bf8_add(acc, r0); bf8_add(acc, r1); bf8_add(acc, r2); bf8_add(acc, r3);
      bf8_add(acc, r4); bf8_add(acc, r5); bf8_add(acc, r6); bf8_add(acc, r7);
    }
    for (; i + 4 <= e; i += 4) {
      int s0 = csrf[i], s1 = csrf[i + 1], s2 = csrf[i + 2], s3 = csrf[i + 3];
      uint4 r0 = bp[(size_t)s0 * 16];
      uint4 r1 = bp[(size_t)s1 * 16];
      uint4 r2 = bp[(size_t)s2 * 16];
      uint4 r3 = bp[(size_t)s3 * 16];
      bf8_add(acc, r0); bf8_add(acc, r1); bf8_add(acc, r2); bf8_add(acc, r3);
    }
    for (; i < e; ++i) bf8_add(acc, bp[(size_t)csrf[i] * 16]);
    float dv = dinv[v];
#pragma unroll
    for (int j = 0; j < 8; ++j) {
      float val = dv * acc[j] + bc2[l * 8 + j];
      s_out[g][l * 8 + j] = val > 0.f ? val : 0.f;
    }
  }
  __syncthreads();
  if (t < 128) {
    int k = t;
    float local = 0.f;
    int cur = s_b[0];
    for (int m = 0; m < GNPB; ++m) {
      int b = s_b[m];
      if (b != cur) {
        atomicAdd(&gsum[cur * 128 + k], local);
        local = 0.f;
        cur = b;
      }
      local += s_out[m][k];
    }
    atomicAdd(&gsum[cur * 128 + k], local);
  }
}

// K5: finalize — mean of relu(out2) half + closed-form out1[root] half
__global__ __launch_bounds__(128) void k_final(
    const float* __restrict__ gsum, const int* __restrict__ start,
    const int* __restrict__ root, const float* __restrict__ dinv,
    const float* __restrict__ sx, const float* __restrict__ sd,
    const float* __restrict__ wc, const float* __restrict__ bcv,
    const float* __restrict__ bc1, float* __restrict__ out) {
  int b = blockIdx.x, k = threadIdx.x;
  int c = start[b + 1] - start[b];
  float cnt = (c < 1) ? 1.f : (float)c;
  out[b * 256 + k] = gsum[b * 128 + k] / cnt;
  int r = root[b];
  float dr = dinv[r];
  float a = dr * sx[r], cc = dr * sd[r];
  out[b * 256 + 128 + k] = a * wc[k] + cc * bcv[k] + bc1[k];
}

extern "C" void kernel_launch(void* const* d_in, const int* in_sizes, int n_in,
                              void* d_out, int out_size, void* d_ws, size_t ws_size,
                              hipStream_t stream) {
  const float* x   = (const float*)d_in[0];
  const int* ei    = (const int*)d_in[1];
  const int* batch = (const int*)d_in[2];
  const int* root  = (const int*)d_in[3];
  const float* W1  = (const float*)d_in[4];
  const float* b1  = (const float*)d_in[5];
  const float* W2  = (const float*)d_in[6];
  const float* b2  = (const float*)d_in[7];
  const float* W3  = (const float*)d_in[8];
  const float* b3  = (const float*)d_in[9];
  const float* Wc1 = (const float*)d_in[10];
  const float* bc1 = (const float*)d_in[11];
  const float* Wc2 = (const float*)d_in[12];
  const float* bc2 = (const float*)d_in[13];
  float* out = (float*)d_out;

  const int* src = ei;            // edge_index[0]
  const int* dst = ei + N_EDGES;  // edge_index[1]

  char* base = (char*)d_ws;
  size_t pos = 0;
  auto alloc = [&](size_t bytes) {
    size_t o = pos;
    pos = (pos + bytes + 255) & ~(size_t)255;
    return (void*)(base + o);
  };
  // cursor, gsum contiguous -> one hipMemsetAsync zeroes both.
  int* cursor = (int*)alloc((size_t)N_NODES * 4);          // 160000 B
  float* gsum = (float*)alloc((size_t)N_GRAPH * 128 * 4);  // 32768 B
  const size_t zero_bytes = (size_t)N_NODES * 4 + (size_t)N_GRAPH * 128 * 4;

  float* wv   = (float*)alloc(64 * 4);
  float* bv   = (float*)alloc(64 * 4);
  float* wc   = (float*)alloc(128 * 4);
  float* bcv  = (float*)alloc(128 * 4);
  float* dinv = (float*)alloc((size_t)N_NODES * 4);
  float* sx   = (float*)alloc((size_t)N_NODES * 4);
  float* sd   = (float*)alloc((size_t)N_NODES * 4);
  int* csrf   = (int*)alloc((size_t)N_NODES * CAP * 4);    // 10.24 MB buckets
  unsigned short* hW2g = (unsigned short*)alloc((size_t)N_NODES * 128 * 2);
  int* start  = (int*)alloc((size_t)(N_GRAPH + 1) * 4);
  __bf16* wc2t = (__bf16*)alloc((size_t)128 * ZDIM * 2);   // fragment-ordered Wc2^T
  (void)ws_size; (void)in_sizes; (void)n_in; (void)out_size;

  const int TB = 256;
  int gE = (N_EDGES + TB - 1) / TB;   // 2500

  hipMemsetAsync(cursor, 0, zero_bytes, stream);
  hipLaunchKernelGGL(k_build, dim3(gE + 1), dim3(TB), 0, stream,
                     src, dst, cursor, csrf, Wc2, wc2t,
                     W1, b1, W2, b2, W3, b3, Wc1, wv, bv, wc, bcv);
  hipLaunchKernelGGL(k_prep2, dim3(40), dim3(256), 0, stream,
                     cursor, dinv, batch, start);
  hipLaunchKernelGGL(k_mlp2, dim3(N_NODES / 64), dim3(256), 0, stream,
                     x, batch, root, dinv, cursor, csrf,
                     wc, bcv, bc1, wv, bv, wc2t, sx, sd, hW2g);
  hipLaunchKernelGGL(k_conv2, dim3(N_NODES / GNPB), dim3(256), 0, stream,
                     cursor, csrf, (const uint4*)hW2g, dinv, bc2, batch, gsum);
  hipLaunchKernelGGL(k_final, dim3(N_GRAPH), dim3(128), 0, stream,
                     gsum, start, root, dinv, sx, sd, wc, bcv, bc1, out);
}

// Round 13
// 105.936 us; speedup vs baseline: 1.1311x; 1.1311x over previous
//
#include <hip/hip_runtime.h>
#include <hip/hip_bf16.h>

#define N_NODES 40000
#define N_EDGES 640000
#define N_GRAPH 64
#define C_IN 64
#define HID 128
#define OUT 128
#define ZDIM 192   // HID + C_IN
#define CAP 64     // fixed bucket stride; P(in-degree > 64) ~ 1e-17, guarded anyway

typedef __bf16 bf16x8 __attribute__((ext_vector_type(8)));
typedef float  f32x4  __attribute__((ext_vector_type(4)));

__device__ __forceinline__ unsigned short f2bf(float f) {
  unsigned u = __float_as_uint(f);
  unsigned r = (u + 0x7FFFu + ((u >> 16) & 1u)) >> 16;
  return (unsigned short)r;
}

__device__ __forceinline__ void bf8_add(float* acc, uint4 r) {
  acc[0] += __uint_as_float(r.x << 16);
  acc[1] += __uint_as_float(r.x & 0xFFFF0000u);
  acc[2] += __uint_as_float(r.y << 16);
  acc[3] += __uint_as_float(r.y & 0xFFFF0000u);
  acc[4] += __uint_as_float(r.z << 16);
  acc[5] += __uint_as_float(r.z & 0xFFFF0000u);
  acc[6] += __uint_as_float(r.w << 16);
  acc[7] += __uint_as_float(r.w & 0xFFFF0000u);
}

__device__ __forceinline__ void bf8_set(float* acc, uint4 r) {
  acc[0] = __uint_as_float(r.x << 16);
  acc[1] = __uint_as_float(r.x & 0xFFFF0000u);
  acc[2] = __uint_as_float(r.y << 16);
  acc[3] = __uint_as_float(r.y & 0xFFFF0000u);
  acc[4] = __uint_as_float(r.z << 16);
  acc[5] = __uint_as_float(r.z & 0xFFFF0000u);
  acc[6] = __uint_as_float(r.w << 16);
  acc[7] = __uint_as_float(r.w & 0xFFFF0000u);
}

// ---------------------------------------------------------------------------
// K1: bucketed CSR build, TWO edges per thread (independent chains -> ILP for
// the store-bound scatter; WRITE_SIZE is line-granule write-allocate).
// Lean kernel: no weight-prep here (R12 showed merging it costs occupancy).
__global__ __launch_bounds__(256) void k_build(
    const int* __restrict__ src, const int* __restrict__ dst,
    int* __restrict__ cursor, int* __restrict__ csrf,
    const float* __restrict__ Wc2, __bf16* __restrict__ wc2t) {
  int t = threadIdx.x;
  int e0 = blockIdx.x * 512 + t;
  int e1 = e0 + 256;
  // fragment-ordered Wc2^T (indices 0..24575)
  if (e0 < 128 * ZDIM) {
    int col = e0 & 127, k = e0 >> 7;
    int ct = col >> 4, lr = col & 15;
    int kk = k >> 5, lg = (k >> 3) & 3, jj = k & 7;
    wc2t[((ct * 6 + kk) * 64 + lg * 16 + lr) * 8 + jj] = (__bf16)Wc2[e0];
  }
  if (e1 < 128 * ZDIM) {
    int col = e1 & 127, k = e1 >> 7;
    int ct = col >> 4, lr = col & 15;
    int kk = k >> 5, lg = (k >> 3) & 3, jj = k & 7;
    wc2t[((ct * 6 + kk) * 64 + lg * 16 + lr) * 8 + jj] = (__bf16)Wc2[e1];
  }
  int d0 = dst[e0], s0 = src[e0];
  int d1 = dst[e1], s1 = src[e1];
  int p0 = atomicAdd(&cursor[d0], 1);
  int p1 = atomicAdd(&cursor[d1], 1);
  if (p0 < CAP) csrf[d0 * CAP + p0] = s0;
  if (p1 < CAP) csrf[d1 * CAP + p1] = s1;
}

// ---------------------------------------------------------------------------
// K2: grid = 41 independent blocks (R11-proven).
//   blocks 0..39 : dinv[v] = rsqrt(deg+1) + per-graph segment bounds.
//   block 40     : weight-prep (LDS-staged, 32KB chunks) -> wv,bv,wc,bcv.
__global__ __launch_bounds__(256) void k_prep2(
    const int* __restrict__ cursor, float* __restrict__ dinv,
    const int* __restrict__ batch, int* __restrict__ start,
    const float* __restrict__ W1, const float* __restrict__ b1,
    const float* __restrict__ W2, const float* __restrict__ b2,
    const float* __restrict__ W3, const float* __restrict__ b3,
    const float* __restrict__ Wc1,
    float* __restrict__ wv, float* __restrict__ bv,
    float* __restrict__ wc, float* __restrict__ bcv) {
  __shared__ __align__(16) float stage[8192];   // 32 KB
  __shared__ float t1[256], u1[256], wv_s[64], bv_s[64], w1s[64], b1s[64];
  int t = threadIdx.x;

  if (blockIdx.x == 40) {
    // ---------------- weight-prep path ----------------
    float4* sv = (float4*)stage;
    float s1 = 0.f, s2 = 0.f;
    if (t < 64) { w1s[t] = W1[t]; b1s[t] = b1[t]; }
    for (int h = 0; h < 2; ++h) {        // t1/u1 = (W1|b1) @ W2
      const float4* W2v = (const float4*)(W2 + h * 32 * 256);
      __syncthreads();
      for (int i = t; i < 2048; i += 256) sv[i] = W2v[i];
      __syncthreads();
      for (int j = 0; j < 32; ++j) {
        float w = stage[j * 256 + t];
        s1 += w1s[h * 32 + j] * w;
        s2 += b1s[h * 32 + j] * w;
      }
    }
    t1[t] = s1;
    u1[t] = s2 + b2[t];
    float a = 0.f, bb = 0.f;
    for (int h = 0; h < 2; ++h) {        // wv/bv = (t1|u1) @ W3 + b3
      const float4* W3v = (const float4*)(W3 + h * 128 * 64);
      __syncthreads();
      for (int i = t; i < 2048; i += 256) sv[i] = W3v[i];
      __syncthreads();
      if (t < 64) {
        for (int k = 0; k < 128; ++k) {
          float w = stage[k * 64 + t];
          a += t1[h * 128 + k] * w;
          bb += u1[h * 128 + k] * w;
        }
      }
    }
    if (t < 64) {
      bb += b3[t];
      wv_s[t] = a; bv_s[t] = bb;
      wv[t] = a;  bv[t] = bb;
    }
    {                                    // wc/bcv = (wv|bv) @ Wc1
      const float4* Wc1v = (const float4*)Wc1;
      __syncthreads();
      for (int i = t; i < 2048; i += 256) sv[i] = Wc1v[i];
      __syncthreads();
      if (t < 128) {
        float aa = 0.f, bb2 = 0.f;
        for (int c = 0; c < 64; ++c) {
          float w = stage[c * 128 + t];
          aa += wv_s[c] * w;
          bb2 += bv_s[c] * w;
        }
        wc[t] = aa; bcv[t] = bb2;
      }
    }
    return;
  }

  // ---------------- dinv + segment-bounds path ----------------
  int base = blockIdx.x * 1024;
  for (int i = 0; i < 4; ++i) {
    int v = base + t * 4 + i;
    if (v < N_NODES) {
      dinv[v] = 1.0f / sqrtf((float)(cursor[v] + 1));
      int bv2 = batch[v];
      if (v == 0) {
        for (int b = 0; b <= bv2; ++b) start[b] = 0;
      } else {
        int bp = batch[v - 1];
        for (int b = bp + 1; b <= bv2; ++b) start[b] = v;
      }
      if (v == N_NODES - 1) {
        for (int b = bv2 + 1; b <= N_GRAPH; ++b) start[b] = N_NODES;
      }
    }
  }
}

// K3 (MFMA, no big LDS): per block = 64 nodes, 256 thr = 4 waves.
__global__ __launch_bounds__(256) void k_mlp2(
    const float* __restrict__ x, const int* __restrict__ batch,
    const int* __restrict__ root, const float* __restrict__ dinv,
    const int* __restrict__ cursor, const int* __restrict__ csrf,
    const float* __restrict__ wc, const float* __restrict__ bcv,
    const float* __restrict__ bc1, const float* __restrict__ wv,
    const float* __restrict__ bv, const __bf16* __restrict__ wc2t,
    float* __restrict__ sx, float* __restrict__ sd,
    unsigned short* __restrict__ hW2g) {
  __shared__ float s_dv[64], s_a[64], s_c[64], s_xr[64];
  int t = threadIdx.x;
  int v0 = blockIdx.x * 64;

  // fused sxsd gather: 4 lanes per node, bucket layout
  {
    int g4 = t >> 2, l4 = t & 3;
    int v = v0 + g4;
    int dg = cursor[v]; if (dg > CAP) dg = CAP;
    int o0 = v * CAP;
    float ax = 0.f, ad = 0.f;
    for (int i = l4; i < dg; i += 4) {
      int s = csrf[o0 + i];
      float ds = dinv[s];
      ax += ds * x[s];
      ad += ds;
    }
    ax += __shfl_xor(ax, 1, 4); ad += __shfl_xor(ad, 1, 4);
    ax += __shfl_xor(ax, 2, 4); ad += __shfl_xor(ad, 2, 4);
    if (l4 == 0) {
      float dv = dinv[v];
      float sxv = ax + dv * x[v];
      float sdv = ad + dv;
      sx[v] = sxv; sd[v] = sdv;
      s_dv[g4] = dv;
      s_a[g4] = dv * sxv;
      s_c[g4] = dv * sdv;
      s_xr[g4] = x[root[batch[v]]];
    }
  }
  __syncthreads();

  int w = t >> 6, l = t & 63;
  int rb = w * 16;
  int lr = l & 15, lg = l >> 4;
  int row = rb + lr;

  // A-fragments in registers: af[kk][j] = relu(z[row][kk*32+lg*8+j]) as bf16.
  float a = s_a[row], c = s_c[row], xr = s_xr[row];
  bf16x8 af[6];
#pragma unroll
  for (int kk = 0; kk < 4; ++kk) {
    int k0 = kk * 32 + lg * 8;
#pragma unroll
    for (int j = 0; j < 8; ++j) {
      float val = a * wc[k0 + j] + c * bcv[k0 + j] + bc1[k0 + j];
      af[kk][j] = (__bf16)(val > 0.f ? val : 0.f);
    }
  }
#pragma unroll
  for (int kk = 4; kk < 6; ++kk) {
    int k0 = (kk - 4) * 32 + lg * 8;
#pragma unroll
    for (int j = 0; j < 8; ++j) {
      float val = xr * wv[k0 + j] + bv[k0 + j];
      af[kk][j] = (__bf16)(val > 0.f ? val : 0.f);
    }
  }

  float dvr[4];
#pragma unroll
  for (int reg = 0; reg < 4; ++reg) dvr[reg] = s_dv[rb + lg * 4 + reg];

  const bf16x8* wt = (const bf16x8*)wc2t;
#pragma unroll
  for (int ct = 0; ct < 8; ++ct) {
    f32x4 acc = {0.f, 0.f, 0.f, 0.f};
#pragma unroll
    for (int kk = 0; kk < 6; ++kk) {
      bf16x8 bf = wt[(ct * 6 + kk) * 64 + l];  // coalesced 16B/lane, L2-hot
      acc = __builtin_amdgcn_mfma_f32_16x16x32_bf16(af[kk], bf, acc, 0, 0, 0);
    }
#pragma unroll
    for (int reg = 0; reg < 4; ++reg) {
      int v = v0 + rb + lg * 4 + reg;
      hW2g[(size_t)v * 128 + ct * 16 + lr] = f2bf(dvr[reg] * acc[reg]);
    }
  }
}

// K4: conv2 gather (bucket CSR, bf16 rows, 16 lanes/row) + relu + per-graph
// partial flush. Latency-bound -> 16-row batched round first (16 independent
// loads in flight), then 8/4/1 tails. No epilogue handshake (fence cost, R10).
#define GNPB 16
__global__ __launch_bounds__(256) void k_conv2(
    const int* __restrict__ cursor, const int* __restrict__ csrf,
    const uint4* __restrict__ hW2g,  // [N][16] uint4 = 128 bf16/row
    const float* __restrict__ dinv, const float* __restrict__ bc2,
    const int* __restrict__ batch, float* __restrict__ gsum) {
  __shared__ float s_out[GNPB][128];
  __shared__ int s_b[GNPB];
  int t = threadIdx.x;
  int g = t >> 4, l = t & 15;
  int v0 = blockIdx.x * GNPB;
  int v = v0 + g;
  if (t < GNPB) s_b[t] = batch[v0 + t];

  {
    const uint4* bp = hW2g + l;
    float acc[8];
    bf8_set(acc, bp[(size_t)v * 16]);    // self-loop row
    int dg = cursor[v]; if (dg > CAP) dg = CAP;
    int i = v * CAP;
    int e = i + dg;
    for (; i + 16 <= e; i += 16) {
      int s[16];
#pragma unroll
      for (int q = 0; q < 16; ++q) s[q] = csrf[i + q];
      uint4 r[16];
#pragma unroll
      for (int q = 0; q < 16; ++q) r[q] = bp[(size_t)s[q] * 16];
#pragma unroll
      for (int q = 0; q < 16; ++q) bf8_add(acc, r[q]);
    }
    for (; i + 8 <= e; i += 8) {
      int s0 = csrf[i],     s1 = csrf[i + 1], s2 = csrf[i + 2], s3 = csrf[i + 3];
      int s4 = csrf[i + 4], s5 = csrf[i + 5], s6 = csrf[i + 6], s7 = csrf[i + 7];
      uint4 r0 = bp[(size_t)s0 * 16];
      uint4 r1 = bp[(size_t)s1 * 16];
      uint4 r2 = bp[(size_t)s2 * 16];
      uint4 r3 = bp[(size_t)s3 * 16];
      uint4 r4 = bp[(size_t)s4 * 16];
      uint4 r5 = bp[(size_t)s5 * 16];
      uint4 r6 = bp[(size_t)s6 * 16];
      uint4 r7 = bp[(size_t)s7 * 16];
      bf8_add(acc, r0); bf8_add(acc, r1); bf8_add(acc, r2); bf8_add(acc, r3);
      bf8_add(acc, r4); bf8_add(acc, r5); bf8_add(acc, r6); bf8_add(acc, r7);
    }
    for (; i + 4 <= e; i += 4) {
      int s0 = csrf[i], s1 = csrf[i + 1], s2 = csrf[i + 2], s3 = csrf[i + 3];
      uint4 r0 = bp[(size_t)s0 * 16];
      uint4 r1 = bp[(size_t)s1 * 16];
      uint4 r2 = bp[(size_t)s2 * 16];
      uint4 r3 = bp[(size_t)s3 * 16];
      bf8_add(acc, r0); bf8_add(acc, r1); bf8_add(acc, r2); bf8_add(acc, r3);
    }
    for (; i < e; ++i) bf8_add(acc, bp[(size_t)csrf[i] * 16]);
    float dv = dinv[v];
#pragma unroll
    for (int j = 0; j < 8; ++j) {
      float val = dv * acc[j] + bc2[l * 8 + j];
      s_out[g][l * 8 + j] = val > 0.f ? val : 0.f;
    }
  }
  __syncthreads();
  if (t < 128) {
    int k = t;
    float local = 0.f;
    int cur = s_b[0];
    for (int m = 0; m < GNPB; ++m) {
      int b = s_b[m];
      if (b != cur) {
        atomicAdd(&gsum[cur * 128 + k], local);
        local = 0.f;
        cur = b;
      }
      local += s_out[m][k];
    }
    atomicAdd(&gsum[cur * 128 + k], local);
  }
}

// K5: finalize — mean of relu(out2) half + closed-form out1[root] half
__global__ __launch_bounds__(128) void k_final(
    const float* __restrict__ gsum, const int* __restrict__ start,
    const int* __restrict__ root, const float* __restrict__ dinv,
    const float* __restrict__ sx, const float* __restrict__ sd,
    const float* __restrict__ wc, const float* __restrict__ bcv,
    const float* __restrict__ bc1, float* __restrict__ out) {
  int b = blockIdx.x, k = threadIdx.x;
  int c = start[b + 1] - start[b];
  float cnt = (c < 1) ? 1.f : (float)c;
  out[b * 256 + k] = gsum[b * 128 + k] / cnt;
  int r = root[b];
  float dr = dinv[r];
  float a = dr * sx[r], cc = dr * sd[r];
  out[b * 256 + 128 + k] = a * wc[k] + cc * bcv[k] + bc1[k];
}

extern "C" void kernel_launch(void* const* d_in, const int* in_sizes, int n_in,
                              void* d_out, int out_size, void* d_ws, size_t ws_size,
                              hipStream_t stream) {
  const float* x   = (const float*)d_in[0];
  const int* ei    = (const int*)d_in[1];
  const int* batch = (const int*)d_in[2];
  const int* root  = (const int*)d_in[3];
  const float* W1  = (const float*)d_in[4];
  const float* b1  = (const float*)d_in[5];
  const float* W2  = (const float*)d_in[6];
  const float* b2  = (const float*)d_in[7];
  const float* W3  = (const float*)d_in[8];
  const float* b3  = (const float*)d_in[9];
  const float* Wc1 = (const float*)d_in[10];
  const float* bc1 = (const float*)d_in[11];
  const float* Wc2 = (const float*)d_in[12];
  const float* bc2 = (const float*)d_in[13];
  float* out = (float*)d_out;

  const int* src = ei;            // edge_index[0]
  const int* dst = ei + N_EDGES;  // edge_index[1]

  char* base = (char*)d_ws;
  size_t pos = 0;
  auto alloc = [&](size_t bytes) {
    size_t o = pos;
    pos = (pos + bytes + 255) & ~(size_t)255;
    return (void*)(base + o);
  };
  // cursor, gsum contiguous -> one hipMemsetAsync zeroes both.
  int* cursor = (int*)alloc((size_t)N_NODES * 4);          // 160000 B
  float* gsum = (float*)alloc((size_t)N_GRAPH * 128 * 4);  // 32768 B
  const size_t zero_bytes = (size_t)N_NODES * 4 + (size_t)N_GRAPH * 128 * 4;

  float* wv   = (float*)alloc(64 * 4);
  float* bv   = (float*)alloc(64 * 4);
  float* wc   = (float*)alloc(128 * 4);
  float* bcv  = (float*)alloc(128 * 4);
  float* dinv = (float*)alloc((size_t)N_NODES * 4);
  float* sx   = (float*)alloc((size_t)N_NODES * 4);
  float* sd   = (float*)alloc((size_t)N_NODES * 4);
  int* csrf   = (int*)alloc((size_t)N_NODES * CAP * 4);    // 10.24 MB buckets
  unsigned short* hW2g = (unsigned short*)alloc((size_t)N_NODES * 128 * 2);
  int* start  = (int*)alloc((size_t)(N_GRAPH + 1) * 4);
  __bf16* wc2t = (__bf16*)alloc((size_t)128 * ZDIM * 2);   // fragment-ordered Wc2^T
  (void)ws_size; (void)in_sizes; (void)n_in; (void)out_size;

  hipMemsetAsync(cursor, 0, zero_bytes, stream);
  hipLaunchKernelGGL(k_build, dim3(N_EDGES / 512), dim3(256), 0, stream,
                     src, dst, cursor, csrf, Wc2, wc2t);
  hipLaunchKernelGGL(k_prep2, dim3(41), dim3(256), 0, stream,
                     cursor, dinv, batch, start,
                     W1, b1, W2, b2, W3, b3, Wc1, wv, bv, wc, bcv);
  hipLaunchKernelGGL(k_mlp2, dim3(N_NODES / 64), dim3(256), 0, stream,
                     x, batch, root, dinv, cursor, csrf,
                     wc, bcv, bc1, wv, bv, wc2t, sx, sd, hW2g);
  hipLaunchKernelGGL(k_conv2, dim3(N_NODES / GNPB), dim3(256), 0, stream,
                     cursor, csrf, (const uint4*)hW2g, dinv, bc2, batch, gsum);
  hipLaunchKernelGGL(k_final, dim3(N_GRAPH), dim3(128), 0, stream,
                     gsum, start, root, dinv, sx, sd, wc, bcv, bc1, out);
}

// Round 14
// 101.904 us; speedup vs baseline: 1.1758x; 1.0396x over previous
//
#include <hip/hip_runtime.h>
#include <hip/hip_bf16.h>

#define N_NODES 40000
#define N_EDGES 640000
#define N_GRAPH 64
#define C_IN 64
#define HID 128
#define OUT 128
#define ZDIM 192   // HID + C_IN
#define CAP 64     // fixed bucket stride; P(in-degree > 64) ~ 1e-17, guarded anyway

typedef __bf16 bf16x8 __attribute__((ext_vector_type(8)));
typedef float  f32x4  __attribute__((ext_vector_type(4)));

__device__ __forceinline__ unsigned short f2bf(float f) {
  unsigned u = __float_as_uint(f);
  unsigned r = (u + 0x7FFFu + ((u >> 16) & 1u)) >> 16;
  return (unsigned short)r;
}

__device__ __forceinline__ void bf8_add(float* acc, uint4 r) {
  acc[0] += __uint_as_float(r.x << 16);
  acc[1] += __uint_as_float(r.x & 0xFFFF0000u);
  acc[2] += __uint_as_float(r.y << 16);
  acc[3] += __uint_as_float(r.y & 0xFFFF0000u);
  acc[4] += __uint_as_float(r.z << 16);
  acc[5] += __uint_as_float(r.z & 0xFFFF0000u);
  acc[6] += __uint_as_float(r.w << 16);
  acc[7] += __uint_as_float(r.w & 0xFFFF0000u);
}

__device__ __forceinline__ void bf8_set(float* acc, uint4 r) {
  acc[0] = __uint_as_float(r.x << 16);
  acc[1] = __uint_as_float(r.x & 0xFFFF0000u);
  acc[2] = __uint_as_float(r.y << 16);
  acc[3] = __uint_as_float(r.y & 0xFFFF0000u);
  acc[4] = __uint_as_float(r.z << 16);
  acc[5] = __uint_as_float(r.z & 0xFFFF0000u);
  acc[6] = __uint_as_float(r.w << 16);
  acc[7] = __uint_as_float(r.w & 0xFFFF0000u);
}

// ---------------------------------------------------------------------------
// K1: bucketed CSR build (R11 shape: one edge/thread). Buckets hold uint16
// node ids (N_NODES < 65536) -> 5.1MB array, halved write-allocate traffic.
// Low threads also build the fragment-ordered bf16 Wc2^T.
__global__ void k_build(const int* __restrict__ src, const int* __restrict__ dst,
                        int* __restrict__ cursor, unsigned short* __restrict__ csrf,
                        const float* __restrict__ Wc2, __bf16* __restrict__ wc2t) {
  int e = blockIdx.x * blockDim.x + threadIdx.x;
  if (e < 128 * ZDIM) {
    int col = e & 127, k = e >> 7;        // coalesced read of Wc2[k*128+col]
    int ct = col >> 4, lr = col & 15;
    int kk = k >> 5, lg = (k >> 3) & 3, jj = k & 7;
    wc2t[((ct * 6 + kk) * 64 + lg * 16 + lr) * 8 + jj] = (__bf16)Wc2[e];
  }
  if (e < N_EDGES) {
    int d = dst[e];
    int p = atomicAdd(&cursor[d], 1);
    if (p < CAP) csrf[d * CAP + p] = (unsigned short)src[e];
  }
}

// ---------------------------------------------------------------------------
// K2: grid = 41 independent blocks (R11-proven).
//   blocks 0..39 : dinv[v] = rsqrt(deg+1) + per-graph segment bounds.
//   block 40     : weight-prep (LDS-staged, 32KB chunks) -> wv,bv,wc,bcv.
__global__ __launch_bounds__(256) void k_prep2(
    const int* __restrict__ cursor, float* __restrict__ dinv,
    const int* __restrict__ batch, int* __restrict__ start,
    const float* __restrict__ W1, const float* __restrict__ b1,
    const float* __restrict__ W2, const float* __restrict__ b2,
    const float* __restrict__ W3, const float* __restrict__ b3,
    const float* __restrict__ Wc1,
    float* __restrict__ wv, float* __restrict__ bv,
    float* __restrict__ wc, float* __restrict__ bcv) {
  __shared__ __align__(16) float stage[8192];   // 32 KB
  __shared__ float t1[256], u1[256], wv_s[64], bv_s[64], w1s[64], b1s[64];
  int t = threadIdx.x;

  if (blockIdx.x == 40) {
    // ---------------- weight-prep path ----------------
    float4* sv = (float4*)stage;
    float s1 = 0.f, s2 = 0.f;
    if (t < 64) { w1s[t] = W1[t]; b1s[t] = b1[t]; }
    for (int h = 0; h < 2; ++h) {        // t1/u1 = (W1|b1) @ W2
      const float4* W2v = (const float4*)(W2 + h * 32 * 256);
      __syncthreads();
      for (int i = t; i < 2048; i += 256) sv[i] = W2v[i];
      __syncthreads();
      for (int j = 0; j < 32; ++j) {
        float w = stage[j * 256 + t];
        s1 += w1s[h * 32 + j] * w;
        s2 += b1s[h * 32 + j] * w;
      }
    }
    t1[t] = s1;
    u1[t] = s2 + b2[t];
    float a = 0.f, bb = 0.f;
    for (int h = 0; h < 2; ++h) {        // wv/bv = (t1|u1) @ W3 + b3
      const float4* W3v = (const float4*)(W3 + h * 128 * 64);
      __syncthreads();
      for (int i = t; i < 2048; i += 256) sv[i] = W3v[i];
      __syncthreads();
      if (t < 64) {
        for (int k = 0; k < 128; ++k) {
          float w = stage[k * 64 + t];
          a += t1[h * 128 + k] * w;
          bb += u1[h * 128 + k] * w;
        }
      }
    }
    if (t < 64) {
      bb += b3[t];
      wv_s[t] = a; bv_s[t] = bb;
      wv[t] = a;  bv[t] = bb;
    }
    {                                    // wc/bcv = (wv|bv) @ Wc1
      const float4* Wc1v = (const float4*)Wc1;
      __syncthreads();
      for (int i = t; i < 2048; i += 256) sv[i] = Wc1v[i];
      __syncthreads();
      if (t < 128) {
        float aa = 0.f, bb2 = 0.f;
        for (int c = 0; c < 64; ++c) {
          float w = stage[c * 128 + t];
          aa += wv_s[c] * w;
          bb2 += bv_s[c] * w;
        }
        wc[t] = aa; bcv[t] = bb2;
      }
    }
    return;
  }

  // ---------------- dinv + segment-bounds path ----------------
  int base = blockIdx.x * 1024;
  for (int i = 0; i < 4; ++i) {
    int v = base + t * 4 + i;
    if (v < N_NODES) {
      dinv[v] = 1.0f / sqrtf((float)(cursor[v] + 1));
      int bv2 = batch[v];
      if (v == 0) {
        for (int b = 0; b <= bv2; ++b) start[b] = 0;
      } else {
        int bp = batch[v - 1];
        for (int b = bp + 1; b <= bv2; ++b) start[b] = v;
      }
      if (v == N_NODES - 1) {
        for (int b = bv2 + 1; b <= N_GRAPH; ++b) start[b] = N_NODES;
      }
    }
  }
}

// K3 (MFMA, no big LDS): per block = 64 nodes, 256 thr = 4 waves.
__global__ __launch_bounds__(256) void k_mlp2(
    const float* __restrict__ x, const int* __restrict__ batch,
    const int* __restrict__ root, const float* __restrict__ dinv,
    const int* __restrict__ cursor, const unsigned short* __restrict__ csrf,
    const float* __restrict__ wc, const float* __restrict__ bcv,
    const float* __restrict__ bc1, const float* __restrict__ wv,
    const float* __restrict__ bv, const __bf16* __restrict__ wc2t,
    float* __restrict__ sx, float* __restrict__ sd,
    unsigned short* __restrict__ hW2g) {
  __shared__ float s_dv[64], s_a[64], s_c[64], s_xr[64];
  int t = threadIdx.x;
  int v0 = blockIdx.x * 64;

  // fused sxsd gather: 4 lanes per node, bucket layout
  {
    int g4 = t >> 2, l4 = t & 3;
    int v = v0 + g4;
    int dg = cursor[v]; if (dg > CAP) dg = CAP;
    int o0 = v * CAP;
    float ax = 0.f, ad = 0.f;
    for (int i = l4; i < dg; i += 4) {
      int s = csrf[o0 + i];
      float ds = dinv[s];
      ax += ds * x[s];
      ad += ds;
    }
    ax += __shfl_xor(ax, 1, 4); ad += __shfl_xor(ad, 1, 4);
    ax += __shfl_xor(ax, 2, 4); ad += __shfl_xor(ad, 2, 4);
    if (l4 == 0) {
      float dv = dinv[v];
      float sxv = ax + dv * x[v];
      float sdv = ad + dv;
      sx[v] = sxv; sd[v] = sdv;
      s_dv[g4] = dv;
      s_a[g4] = dv * sxv;
      s_c[g4] = dv * sdv;
      s_xr[g4] = x[root[batch[v]]];
    }
  }
  __syncthreads();

  int w = t >> 6, l = t & 63;
  int rb = w * 16;
  int lr = l & 15, lg = l >> 4;
  int row = rb + lr;

  // A-fragments in registers: af[kk][j] = relu(z[row][kk*32+lg*8+j]) as bf16.
  float a = s_a[row], c = s_c[row], xr = s_xr[row];
  bf16x8 af[6];
#pragma unroll
  for (int kk = 0; kk < 4; ++kk) {
    int k0 = kk * 32 + lg * 8;
#pragma unroll
    for (int j = 0; j < 8; ++j) {
      float val = a * wc[k0 + j] + c * bcv[k0 + j] + bc1[k0 + j];
      af[kk][j] = (__bf16)(val > 0.f ? val : 0.f);
    }
  }
#pragma unroll
  for (int kk = 4; kk < 6; ++kk) {
    int k0 = (kk - 4) * 32 + lg * 8;
#pragma unroll
    for (int j = 0; j < 8; ++j) {
      float val = xr * wv[k0 + j] + bv[k0 + j];
      af[kk][j] = (__bf16)(val > 0.f ? val : 0.f);
    }
  }

  float dvr[4];
#pragma unroll
  for (int reg = 0; reg < 4; ++reg) dvr[reg] = s_dv[rb + lg * 4 + reg];

  const bf16x8* wt = (const bf16x8*)wc2t;
#pragma unroll
  for (int ct = 0; ct < 8; ++ct) {
    f32x4 acc = {0.f, 0.f, 0.f, 0.f};
#pragma unroll
    for (int kk = 0; kk < 6; ++kk) {
      bf16x8 bf = wt[(ct * 6 + kk) * 64 + l];  // coalesced 16B/lane, L2-hot
      acc = __builtin_amdgcn_mfma_f32_16x16x32_bf16(af[kk], bf, acc, 0, 0, 0);
    }
#pragma unroll
    for (int reg = 0; reg < 4; ++reg) {
      int v = v0 + rb + lg * 4 + reg;
      hW2g[(size_t)v * 128 + ct * 16 + lr] = f2bf(dvr[reg] * acc[reg]);
    }
  }
}

// K4: conv2 gather (bucket CSR, bf16 rows, 16 lanes/row, unroll-8) + relu
//     + per-graph partial flush (R11-proven shape; 16-batch variant regressed
//     in R13 -- VGPR growth cut waves/SIMD). Fetch is pinned at ~1.4 TB/s
//     compulsory cross-XCD traffic; do not add ILP at occupancy's expense.
#define GNPB 16
__global__ __launch_bounds__(256) void k_conv2(
    const int* __restrict__ cursor, const unsigned short* __restrict__ csrf,
    const uint4* __restrict__ hW2g,  // [N][16] uint4 = 128 bf16/row
    const float* __restrict__ dinv, const float* __restrict__ bc2,
    const int* __restrict__ batch, float* __restrict__ gsum) {
  __shared__ float s_out[GNPB][128];
  __shared__ int s_b[GNPB];
  int t = threadIdx.x;
  int g = t >> 4, l = t & 15;
  int v0 = blockIdx.x * GNPB;
  int v = v0 + g;
  if (t < GNPB) s_b[t] = batch[v0 + t];

  {
    const uint4* bp = hW2g + l;
    float acc[8];
    bf8_set(acc, bp[(size_t)v * 16]);    // self-loop row
    int dg = cursor[v]; if (dg > CAP) dg = CAP;
    int i = v * CAP;
    int e = i + dg;
    for (; i + 8 <= e; i += 8) {
      int s0 = csrf[i],     s1 = csrf[i + 1], s2 = csrf[i + 2], s3 = csrf[i + 3];
      int s4 = csrf[i + 4], s5 = csrf[i + 5], s6 = csrf[i + 6], s7 = csrf[i + 7];
      uint4 r0 = bp[(size_t)s0 * 16];
      uint4 r1 = bp[(size_t)s1 * 16];
      uint4 r2 = bp[(size_t)s2 * 16];
      uint4 r3 = bp[(size_t)s3 * 16];
      uint4 r4 = bp[(size_t)s4 * 16];
      uint4 r5 = bp[(size_t)s5 * 16];
      uint4 r6 = bp[(size_t)s6 * 16];
      uint4 r7 = bp[(size_t)s7 * 16];
      bf8_add(acc, r0); bf8_add(acc, r1); bf8_add(acc, r2); bf8_add(acc, r3);
      bf8_add(acc, r4); bf8_add(acc, r5); bf8_add(acc, r6); bf8_add(acc, r7);
    }
    for (; i + 4 <= e; i += 4) {
      int s0 = csrf[i], s1 = csrf[i + 1], s2 = csrf[i + 2], s3 = csrf[i + 3];
      uint4 r0 = bp[(size_t)s0 * 16];
      uint4 r1 = bp[(size_t)s1 * 16];
      uint4 r2 = bp[(size_t)s2 * 16];
      uint4 r3 = bp[(size_t)s3 * 16];
      bf8_add(acc, r0); bf8_add(acc, r1); bf8_add(acc, r2); bf8_add(acc, r3);
    }
    for (; i < e; ++i) bf8_add(acc, bp[(size_t)csrf[i] * 16]);
    float dv = dinv[v];
#pragma unroll
    for (int j = 0; j < 8; ++j) {
      float val = dv * acc[j] + bc2[l * 8 + j];
      s_out[g][l * 8 + j] = val > 0.f ? val : 0.f;
    }
  }
  __syncthreads();
  if (t < 128) {
    int k = t;
    float local = 0.f;
    int cur = s_b[0];
    for (int m = 0; m < GNPB; ++m) {
      int b = s_b[m];
      if (b != cur) {
        atomicAdd(&gsum[cur * 128 + k], local);
        local = 0.f;
        cur = b;
      }
      local += s_out[m][k];
    }
    atomicAdd(&gsum[cur * 128 + k], local);
  }
}

// K5: finalize — mean of relu(out2) half + closed-form out1[root] half
__global__ __launch_bounds__(128) void k_final(
    const float* __restrict__ gsum, const int* __restrict__ start,
    const int* __restrict__ root, const float* __restrict__ dinv,
    const float* __restrict__ sx, const float* __restrict__ sd,
    const float* __restrict__ wc, const float* __restrict__ bcv,
    const float* __restrict__ bc1, float* __restrict__ out) {
  int b = blockIdx.x, k = threadIdx.x;
  int c = start[b + 1] - start[b];
  float cnt = (c < 1) ? 1.f : (float)c;
  out[b * 256 + k] = gsum[b * 128 + k] / cnt;
  int r = root[b];
  float dr = dinv[r];
  float a = dr * sx[r], cc = dr * sd[r];
  out[b * 256 + 128 + k] = a * wc[k] + cc * bcv[k] + bc1[k];
}

extern "C" void kernel_launch(void* const* d_in, const int* in_sizes, int n_in,
                              void* d_out, int out_size, void* d_ws, size_t ws_size,
                              hipStream_t stream) {
  const float* x   = (const float*)d_in[0];
  const int* ei    = (const int*)d_in[1];
  const int* batch = (const int*)d_in[2];
  const int* root  = (const int*)d_in[3];
  const float* W1  = (const float*)d_in[4];
  const float* b1  = (const float*)d_in[5];
  const float* W2  = (const float*)d_in[6];
  const float* b2  = (const float*)d_in[7];
  const float* W3  = (const float*)d_in[8];
  const float* b3  = (const float*)d_in[9];
  const float* Wc1 = (const float*)d_in[10];
  const float* bc1 = (const float*)d_in[11];
  const float* Wc2 = (const float*)d_in[12];
  const float* bc2 = (const float*)d_in[13];
  float* out = (float*)d_out;

  const int* src = ei;            // edge_index[0]
  const int* dst = ei + N_EDGES;  // edge_index[1]

  char* base = (char*)d_ws;
  size_t pos = 0;
  auto alloc = [&](size_t bytes) {
    size_t o = pos;
    pos = (pos + bytes + 255) & ~(size_t)255;
    return (void*)(base + o);
  };
  // cursor, gsum contiguous -> one hipMemsetAsync zeroes both.
  int* cursor = (int*)alloc((size_t)N_NODES * 4);          // 160000 B
  float* gsum = (float*)alloc((size_t)N_GRAPH * 128 * 4);  // 32768 B
  const size_t zero_bytes = (size_t)N_NODES * 4 + (size_t)N_GRAPH * 128 * 4;

  float* wv   = (float*)alloc(64 * 4);
  float* bv   = (float*)alloc(64 * 4);
  float* wc   = (float*)alloc(128 * 4);
  float* bcv  = (float*)alloc(128 * 4);
  float* dinv = (float*)alloc((size_t)N_NODES * 4);
  float* sx   = (float*)alloc((size_t)N_NODES * 4);
  float* sd   = (float*)alloc((size_t)N_NODES * 4);
  unsigned short* csrf = (unsigned short*)alloc((size_t)N_NODES * CAP * 2); // 5.1MB
  unsigned short* hW2g = (unsigned short*)alloc((size_t)N_NODES * 128 * 2);
  int* start  = (int*)alloc((size_t)(N_GRAPH + 1) * 4);
  __bf16* wc2t = (__bf16*)alloc((size_t)128 * ZDIM * 2);   // fragment-ordered Wc2^T
  (void)ws_size; (void)in_sizes; (void)n_in; (void)out_size;

  const int TB = 256;
  int gE = (N_EDGES + TB - 1) / TB;   // 2500

  hipMemsetAsync(cursor, 0, zero_bytes, stream);
  hipLaunchKernelGGL(k_build, dim3(gE), dim3(TB), 0, stream,
                     src, dst, cursor, csrf, Wc2, wc2t);
  hipLaunchKernelGGL(k_prep2, dim3(41), dim3(256), 0, stream,
                     cursor, dinv, batch, start,
                     W1, b1, W2, b2, W3, b3, Wc1, wv, bv, wc, bcv);
  hipLaunchKernelGGL(k_mlp2, dim3(N_NODES / 64), dim3(256), 0, stream,
                     x, batch, root, dinv, cursor, csrf,
                     wc, bcv, bc1, wv, bv, wc2t, sx, sd, hW2g);
  hipLaunchKernelGGL(k_conv2, dim3(N_NODES / GNPB), dim3(256), 0, stream,
                     cursor, csrf, (const uint4*)hW2g, dinv, bc2, batch, gsum);
  hipLaunchKernelGGL(k_final, dim3(N_GRAPH), dim3(128), 0, stream,
                     gsum, start, root, dinv, sx, sd, wc, bcv, bc1, out);
}